// Round 5
// baseline (276.975 us; speedup 1.0000x reference)
//
#include <hip/hip_runtime.h>
#include <hip/hip_bf16.h>

constexpr int kB = 8, kN = 8192, kS = 2048;
constexpr int kD1 = 128, kD2 = 256, kCin = 384, kM0 = 256, kM1 = 128;
constexpr float kEps = 1e-5f;

typedef float f32x4 __attribute__((ext_vector_type(4)));
typedef short bf16x8 __attribute__((ext_vector_type(8)));
typedef unsigned short u16x4 __attribute__((ext_vector_type(4)));

__device__ inline unsigned short f2bf(float f) {
    __hip_bfloat16 h = __float2bfloat16(f);
    return *reinterpret_cast<unsigned short*>(&h);
}
__device__ inline float bf2f(unsigned short u) {
    unsigned int v = (unsigned int)u << 16;
    return *reinterpret_cast<float*>(&v);
}

// ------- Transpose points2 [b][c][s] -> p2t [b][s][c] (f32), + spk prep ----
// spk[b][s] = (sx, sy, sz, |s|^2): the wave-uniform source table the knn
// kernel streams through the SCALAR path (s_load), keeping VALU/LDS free.
__global__ __launch_bounds__(256) void transpose_p2_kernel(
    const float* __restrict__ in, float* __restrict__ out,
    const float* __restrict__ xyz2, f32x4* __restrict__ spk)
{
    __shared__ float tl[64][69];
    const int s0 = blockIdx.x * 64, c0 = blockIdx.y * 64, b = blockIdx.z;
    const int t = threadIdx.x;
    const int rlo = t >> 4, rhi = t & 15;
    if (blockIdx.x == 0 && blockIdx.y == 0) {   // fold source-table prep in
        const float* x2 = xyz2 + b * 3 * kS;
        for (int s = t; s < kS; s += 256) {
            float sx = x2[s], sy = x2[kS + s], sz = x2[2 * kS + s];
            f32x4 q = {sx, sy, sz, fmaf(sx, sx, fmaf(sy, sy, sz * sz))};
            spk[b * kS + s] = q;
        }
    }
#pragma unroll
    for (int r = 0; r < 4; ++r) {
        const int cl = rlo + r * 16;
        f32x4 v = *(const f32x4*)(in + ((size_t)(b * kD2 + c0 + cl)) * kS + s0 + rhi * 4);
#pragma unroll
        for (int j = 0; j < 4; ++j) tl[cl][rhi * 4 + j] = v[j];
    }
    __syncthreads();
#pragma unroll
    for (int r = 0; r < 4; ++r) {
        const int sl = rlo + r * 16;
        f32x4 v;
#pragma unroll
        for (int j = 0; j < 4; ++j) v[j] = tl[rhi * 4 + j][sl];
        *(f32x4*)(out + ((size_t)(b * kS + s0 + sl)) * kD2 + c0 + rhi * 4) = v;
    }
}

// ------------- Transpose points1 [b][c][n] -> xt[b][n][256+c] (bf16) -------
__global__ __launch_bounds__(256) void transpose_p1_kernel(
    const float* __restrict__ in, unsigned short* __restrict__ xt)
{
    __shared__ float tl[64][69];
    const int n0 = blockIdx.x * 64, c0 = blockIdx.y * 64, b = blockIdx.z;
    const int t = threadIdx.x;
    const int rlo = t >> 4, rhi = t & 15;
#pragma unroll
    for (int r = 0; r < 4; ++r) {
        const int cl = rlo + r * 16;
        f32x4 v = *(const f32x4*)(in + ((size_t)(b * kD1 + c0 + cl)) * kN + n0 + rhi * 4);
#pragma unroll
        for (int j = 0; j < 4; ++j) tl[cl][rhi * 4 + j] = v[j];
    }
    __syncthreads();
#pragma unroll
    for (int r = 0; r < 4; ++r) {
        const int nl = rlo + r * 16;
        u16x4 u;
#pragma unroll
        for (int j = 0; j < 4; ++j) u[j] = f2bf(tl[rhi * 4 + j][nl]);
        *(u16x4*)(xt + ((size_t)(b * kN + n0 + nl)) * kCin + 256 + c0 + rhi * 4) = u;
    }
}

// ---------------- 3-NN + interp: scalar-path sources, 1 query/lane ---------
// Block = 4 waves x 64 lanes = 64 queries; wave w scans sources [512w,512w+512).
// Source reads are wave-uniform (loop-var index into spk) -> s_load_dwordx4 on
// the SMEM pipe: the round-3/4 bottleneck (4.2M ds_read_b128, ~12cyc each on
// the LDS pipe) disappears; hot loop is ~5 VALU/elem.
// pass1: 4 rotating fp32 min-chains of reduced dist d' = |s|^2 - 2p.s
//        (order-preserving). Bound: 3 smallest of the 4 chain minima are 3
//        distinct elements => 3rd-smallest chain-min >= true subset d'_(3).
//        cutoff = bound + 1e-3 (fp32 err ~1e-5: margin ~100x, validated r1-4).
// pass2: rescan subset; df <= cutoff -> exact fp64 insert with global index,
//        strict '<' (stable ties). Cross-wave merge of exact triples via LDS
//        with (d, idx) lexicographic order, then quad-cooperative gather.
__global__ __launch_bounds__(256) void knn_interp_kernel(
    const float* __restrict__ xyz1, const f32x4* __restrict__ spk,
    const float* __restrict__ p2t, unsigned short* __restrict__ xt)
{
    __shared__ double md[4][64][3];
    __shared__ int    mi[4][64][3];
    __shared__ float  gw[64][3];
    __shared__ int    gi[64][3];
    const int b = blockIdx.x >> 7;           // 128 blocks per batch
    const int n0 = (blockIdx.x & 127) << 6;  // 64 queries per block
    const int t = threadIdx.x;
    const int w = t >> 6, l = t & 63;
    const int n = n0 + l;
    const float* x1 = xyz1 + b * 3 * kN;
    const float px = x1[n], py = x1[kN + n], pz = x1[2 * kN + n];
    const float ax = -2.f * px, ay = -2.f * py, az = -2.f * pz;
    const f32x4* sb = spk + b * kS + w * 512;   // this wave's source subset

    // ---- pass 1: 4 rotating min-chains (1 fmin/elem, ILP across chains)
    float c0 = 1e30f, c1 = 1e30f, c2 = 1e30f, c3 = 1e30f;
#pragma unroll 2
    for (int i = 0; i < 512; i += 4) {
        f32x4 q0 = sb[i], q1 = sb[i + 1], q2 = sb[i + 2], q3 = sb[i + 3];
        float e0 = fmaf(ax, q0[0], fmaf(ay, q0[1], fmaf(az, q0[2], q0[3])));
        float e1 = fmaf(ax, q1[0], fmaf(ay, q1[1], fmaf(az, q1[2], q1[3])));
        float e2 = fmaf(ax, q2[0], fmaf(ay, q2[1], fmaf(az, q2[2], q2[3])));
        float e3 = fmaf(ax, q3[0], fmaf(ay, q3[1], fmaf(az, q3[2], q3[3])));
        c0 = fminf(c0, e0); c1 = fminf(c1, e1);
        c2 = fminf(c2, e2); c3 = fminf(c3, e3);
    }
    // 3rd-smallest of the 4 chain minima (= 2nd largest of 4)
    const float hi1 = fmaxf(c0, c1), lo1 = fminf(c0, c1);
    const float hi2 = fmaxf(c2, c3), lo2 = fminf(c2, c3);
    const float bound3 = fmaxf(fminf(hi1, hi2), fmaxf(lo1, lo2));
    const float cutoff = bound3 + 1e-3f;

    // ---- pass 2: exact fp64 top-3 (global indices) among filtered candidates
    double d0 = 1e300, d1 = 1e300, d2 = 1e300;
    int i0 = 0, i1 = 0, i2 = 0;
    const double dpx = (double)px, dpy = (double)py, dpz = (double)pz;
#pragma unroll 4
    for (int i = 0; i < 512; ++i) {
        f32x4 q = sb[i];
        float df = fmaf(ax, q[0], fmaf(ay, q[1], fmaf(az, q[2], q[3])));
        if (df <= cutoff) {
            const int s = w * 512 + i;
            double ex = dpx - (double)q[0], ey = dpy - (double)q[1], ez = dpz - (double)q[2];
            double d = ex * ex + ey * ey + ez * ez;
            if (d < d2) {
                if (d < d1) {
                    if (d < d0) { d2 = d1; i2 = i1; d1 = d0; i1 = i0; d0 = d; i0 = s; }
                    else        { d2 = d1; i2 = i1; d1 = d;  i1 = s; }
                } else          { d2 = d;  i2 = s; }
            }
        }
    }
    md[w][l][0] = d0; md[w][l][1] = d1; md[w][l][2] = d2;
    mi[w][l][0] = i0; mi[w][l][1] = i1; mi[w][l][2] = i2;
    __syncthreads();

    // ---- cross-wave merge (wave 0), weights, publish to LDS
    if (w == 0) {
#pragma unroll
        for (int ww = 1; ww < 4; ++ww) {
#pragma unroll
            for (int m = 0; m < 3; ++m) {
                double pd = md[ww][l][m];
                int pi = mi[ww][l][m];
                if (pd < d2 || (pd == d2 && pi < i2)) {
                    if (pd < d1 || (pd == d1 && pi < i1)) {
                        if (pd < d0 || (pd == d0 && pi < i0)) {
                            d2 = d1; i2 = i1; d1 = d0; i1 = i0; d0 = pd; i0 = pi;
                        } else { d2 = d1; i2 = i1; d1 = pd; i1 = pi; }
                    } else { d2 = pd; i2 = pi; }
                }
            }
        }
        const double r0 = 1.0 / (d0 + 1e-8), r1 = 1.0 / (d1 + 1e-8), r2 = 1.0 / (d2 + 1e-8);
        const double rs = 1.0 / (r0 + r1 + r2);
        gw[l][0] = (float)(r0 * rs); gw[l][1] = (float)(r1 * rs); gw[l][2] = (float)(r2 * rs);
        gi[l][0] = i0; gi[l][1] = i1; gi[l][2] = i2;
    }
    __syncthreads();

    // ---- gather: 3 contiguous 1 KB p2t rows per query, quad-cooperative
    const int q = t >> 2, c4 = t & 3;
    const int nn = n0 + q;
    const float ww0 = gw[q][0], ww1 = gw[q][1], ww2 = gw[q][2];
    const f32x4* row0 = (const f32x4*)(p2t + ((size_t)(b * kS) + gi[q][0]) * kD2);
    const f32x4* row1 = (const f32x4*)(p2t + ((size_t)(b * kS) + gi[q][1]) * kD2);
    const f32x4* row2 = (const f32x4*)(p2t + ((size_t)(b * kS) + gi[q][2]) * kD2);
    unsigned short* dst = xt + ((size_t)(b * kN) + nn) * kCin;
#pragma unroll 4
    for (int j = 0; j < 16; ++j) {
        const int ch = c4 + 4 * j;                  // f32x4 chunk index (0..63)
        f32x4 v = ww0 * row0[ch] + ww1 * row1[ch] + ww2 * row2[ch];
        u16x4 u = {f2bf(v[0]), f2bf(v[1]), f2bf(v[2]), f2bf(v[3])};
        *(u16x4*)(dst + ch * 4) = u;
    }
}

// ---------------- bf16 MFMA GEMM + BN-stats --------------------------------
// X rows [n][K] bf16. W [MTOT][K] f32 -> bf16 on stage. 128x128 tile, 4 waves,
// 16x16x32 MFMA, XOR-swizzled LDS.
// BNRELU: apply input-side scale/shift + relu while staging X.
// OUTMODE: 0 = bf16 Yb[b][n][m]; 2 = no store (stats-only pass);
//          3 = f32 Yf[b][m][n] with output-side scaleO/shiftO + relu.
__device__ inline int swz(int row, int ks) {   // ushort index of a 16B slot
    return row * 32 + ((ks ^ ((row >> 1) & 3)) << 3);
}

template <int K, int MTOT, bool BNRELU, int OUTMODE, bool STATS>
__global__ __launch_bounds__(256) void gemm_bn_kernel(
    const float* __restrict__ W, const unsigned short* __restrict__ X,
    const float* __restrict__ scale, const float* __restrict__ shift,
    const float* __restrict__ scaleO, const float* __restrict__ shiftO,
    unsigned short* __restrict__ Yb, float* __restrict__ Yf,
    float* __restrict__ gsum, float* __restrict__ gsq)
{
    constexpr int BM = 128, BN = 128;
    __shared__ unsigned short Al[BM * 32], Bl[BN * 32];   // 8 KB each, swizzled
    __shared__ float ssum[BM], ssq[BM];
    __shared__ float s_sc[K > 0 ? K : 1], s_sh[K > 0 ? K : 1];
    __shared__ float s_scO[BM], s_shO[BM];
    const int t = threadIdx.x;
    const int bn = blockIdx.x * BN, bo = blockIdx.y * BM, b = blockIdx.z;
    const int l = t & 63, w = t >> 6;
    const int wm = (w >> 1) * 64, wn = (w & 1) * 64;
    const int lrow = l & 15, lks = l >> 4;

    if constexpr (BNRELU) {
        if (t < K) { s_sc[t] = scale[t]; s_sh[t] = shift[t]; }
    }
    if constexpr (OUTMODE == 3) {
        if (t < BM) { s_scO[t] = scaleO[bo + t]; s_shO[t] = shiftO[bo + t]; }
    }
    if constexpr (STATS) {
        if (t < BM) { ssum[t] = 0.f; ssq[t] = 0.f; }
    }
    __syncthreads();

    f32x4 acc[4][4] = {};
    for (int k0 = 0; k0 < K; k0 += 32) {
#pragma unroll
        for (int r = 0; r < 2; ++r) {
            const int sid = t + r * 256;
            const int m = sid >> 2, ks = sid & 3;
            const float* wp = W + (size_t)(bo + m) * K + k0 + ks * 8;
            f32x4 wa = *(const f32x4*)wp, wb = *(const f32x4*)(wp + 4);
            bf16x8 u;
#pragma unroll
            for (int j = 0; j < 4; ++j) { u[j] = (short)f2bf(wa[j]); u[j + 4] = (short)f2bf(wb[j]); }
            *(bf16x8*)(Al + swz(m, ks)) = u;
        }
#pragma unroll
        for (int r = 0; r < 2; ++r) {
            const int sid = t + r * 256;
            const int nl = sid >> 2, ks = sid & 3;
            bf16x8 v = *(const bf16x8*)(X + ((size_t)(b * kN) + bn + nl) * K + k0 + ks * 8);
            if constexpr (BNRELU) {
#pragma unroll
                for (int j = 0; j < 8; ++j) {
                    const int ch = k0 + ks * 8 + j;
                    float f = fmaxf(fmaf(bf2f((unsigned short)v[j]), s_sc[ch], s_sh[ch]), 0.f);
                    v[j] = (short)f2bf(f);
                }
            }
            *(bf16x8*)(Bl + swz(nl, ks)) = v;
        }
        __syncthreads();
        bf16x8 af[4], bfr[4];
#pragma unroll
        for (int f = 0; f < 4; ++f) af[f]  = *(const bf16x8*)(Al + swz(wm + f * 16 + lrow, lks));
#pragma unroll
        for (int f = 0; f < 4; ++f) bfr[f] = *(const bf16x8*)(Bl + swz(wn + f * 16 + lrow, lks));
#pragma unroll
        for (int mi = 0; mi < 4; ++mi)
#pragma unroll
            for (int ni = 0; ni < 4; ++ni)
                acc[mi][ni] = __builtin_amdgcn_mfma_f32_16x16x32_bf16(af[mi], bfr[ni], acc[mi][ni], 0, 0, 0);
        __syncthreads();
    }

    if constexpr (STATS) {
#pragma unroll
        for (int mi = 0; mi < 4; ++mi) {
#pragma unroll
            for (int r = 0; r < 4; ++r) {
                float ps = 0.f, pq = 0.f;
#pragma unroll
                for (int ni = 0; ni < 4; ++ni) { float v = acc[mi][ni][r]; ps += v; pq += v * v; }
#pragma unroll
                for (int off = 1; off < 16; off <<= 1) { ps += __shfl_xor(ps, off); pq += __shfl_xor(pq, off); }
                if (lrow == 0) {
                    const int m = wm + mi * 16 + lks * 4 + r;
                    atomicAdd(&ssum[m], ps); atomicAdd(&ssq[m], pq);
                }
            }
        }
    }

    if constexpr (OUTMODE == 0) {
#pragma unroll
        for (int mi = 0; mi < 4; ++mi)
#pragma unroll
            for (int ni = 0; ni < 4; ++ni) {
                const int m = bo + wm + mi * 16 + lks * 4;
                const int n = bn + wn + ni * 16 + lrow;
                u16x4 u = {f2bf(acc[mi][ni][0]), f2bf(acc[mi][ni][1]),
                           f2bf(acc[mi][ni][2]), f2bf(acc[mi][ni][3])};
                *(u16x4*)(Yb + ((size_t)(b * kN) + n) * MTOT + m) = u;
            }
    } else if constexpr (OUTMODE == 3) {
#pragma unroll
        for (int mi = 0; mi < 4; ++mi)
#pragma unroll
            for (int ni = 0; ni < 4; ++ni) {
                const int n = bn + wn + ni * 16 + lrow;
#pragma unroll
                for (int r = 0; r < 4; ++r) {
                    const int ml = wm + mi * 16 + lks * 4 + r;
                    float v = fmaxf(fmaf(acc[mi][ni][r], s_scO[ml], s_shO[ml]), 0.f);
                    Yf[((size_t)(b * MTOT) + bo + ml) * kN + n] = v;
                }
            }
    }
    if constexpr (STATS) {
        __syncthreads();
        if (t < BM) {
            atomicAdd(&gsum[bo + t], ssum[t]);
            atomicAdd(&gsq[bo + t], ssq[t]);
        }
    }
}

// ---------------- BN stat finalize -----------------------------------------
__global__ void bn_finalize_kernel(const float* __restrict__ gsum, const float* __restrict__ gsq,
                                   const float* __restrict__ g, const float* __restrict__ be,
                                   float* __restrict__ scale, float* __restrict__ shift, int M)
{
    int t = threadIdx.x;
    if (t < M) {
        const float invn = 1.0f / 65536.0f;
        float mean = gsum[t] * invn;
        float var = gsq[t] * invn - mean * mean;   // biased var
        float sc = g[t] * rsqrtf(var + kEps);
        scale[t] = sc;
        shift[t] = fmaf(-mean, sc, be[t]);
    }
}

extern "C" void kernel_launch(void* const* d_in, const int* in_sizes, int n_in,
                              void* d_out, int out_size, void* d_ws, size_t ws_size,
                              hipStream_t stream)
{
    const float* xyz1    = (const float*)d_in[0];
    const float* xyz2    = (const float*)d_in[1];
    const float* points1 = (const float*)d_in[2];
    const float* points2 = (const float*)d_in[3];
    const float* w0      = (const float*)d_in[4];
    // d_in[5] = b0, d_in[9] = b1: conv biases cancel in BatchNorm -> unused
    const float* g0      = (const float*)d_in[6];
    const float* be0     = (const float*)d_in[7];
    const float* w1      = (const float*)d_in[8];
    const float* g1      = (const float*)d_in[10];
    const float* be1     = (const float*)d_in[11];
    float* out = (float*)d_out;

    char* ws = (char*)d_ws;
    unsigned short* xt  = (unsigned short*)ws;                           // 48 MiB  [B][N][384] bf16
    float* p2t          = (float*)(ws + (size_t)50331648);               // 16 MiB  [B][S][256] f32
    unsigned short* y0t = (unsigned short*)(ws + (size_t)67108864);      // 32 MiB  [B][N][256] bf16
    float* stats        = (float*)(ws + (size_t)100663296);              // ~6 KB
    f32x4* spk          = (f32x4*)(ws + (size_t)104857600);              // 256 KiB [B][S] packed
    float* sum0 = stats,          *sq0 = stats + 256;
    float* sum1 = stats + 512,    *sq1 = stats + 640;
    float* scale0 = stats + 768,  *shift0 = stats + 1024;
    float* scale1 = stats + 1280, *shift1 = stats + 1408;

    hipMemsetAsync(stats, 0, 768 * sizeof(float), stream);
    transpose_p2_kernel<<<dim3(32, 4, 8), 256, 0, stream>>>(points2, p2t, xyz2, spk);
    transpose_p1_kernel<<<dim3(128, 2, 8), 256, 0, stream>>>(points1, xt);
    knn_interp_kernel<<<1024, 256, 0, stream>>>(xyz1, spk, p2t, xt);
    gemm_bn_kernel<kCin, kM0, false, 0, true><<<dim3(64, 2, 8), 256, 0, stream>>>(
        w0, xt, nullptr, nullptr, nullptr, nullptr, y0t, nullptr, sum0, sq0);
    bn_finalize_kernel<<<1, 256, 0, stream>>>(sum0, sq0, g0, be0, scale0, shift0, 256);
    gemm_bn_kernel<kM0, kM1, true, 2, true><<<dim3(64, 1, 8), 256, 0, stream>>>(
        w1, y0t, scale0, shift0, nullptr, nullptr, nullptr, nullptr, sum1, sq1);
    bn_finalize_kernel<<<1, 128, 0, stream>>>(sum1, sq1, g1, be1, scale1, shift1, 128);
    gemm_bn_kernel<kM0, kM1, true, 3, false><<<dim3(64, 1, 8), 256, 0, stream>>>(
        w1, y0t, scale0, shift0, scale1, shift1, nullptr, out, nullptr, nullptr);
}

// Round 6
// 235.897 us; speedup vs baseline: 1.1741x; 1.1741x over previous
//
#include <hip/hip_runtime.h>
#include <hip/hip_bf16.h>

constexpr int kB = 8, kN = 8192, kS = 2048;
constexpr int kD1 = 128, kD2 = 256, kCin = 384, kM0 = 256, kM1 = 128;
constexpr float kEps = 1e-5f;

typedef float f32x4 __attribute__((ext_vector_type(4)));
typedef short bf16x8 __attribute__((ext_vector_type(8)));
typedef unsigned short u16x4 __attribute__((ext_vector_type(4)));

__device__ inline unsigned short f2bf(float f) {
    __hip_bfloat16 h = __float2bfloat16(f);
    return *reinterpret_cast<unsigned short*>(&h);
}
__device__ inline float bf2f(unsigned short u) {
    unsigned int v = (unsigned int)u << 16;
    return *reinterpret_cast<float*>(&v);
}
__device__ inline float rdlane(float v, int j) {   // wave-uniform broadcast, VALU-domain
    return __int_as_float(__builtin_amdgcn_readlane(__float_as_int(v), j));
}

// ------- Transpose points2 [b][c][s] -> p2t [b][s][c] (f32), + spk prep ----
// spk[b][s] = (sx, sy, sz, |s|^2): packed source table, 32 KB/batch (L2-hot).
__global__ __launch_bounds__(256) void transpose_p2_kernel(
    const float* __restrict__ in, float* __restrict__ out,
    const float* __restrict__ xyz2, f32x4* __restrict__ spk)
{
    __shared__ float tl[64][69];
    const int s0 = blockIdx.x * 64, c0 = blockIdx.y * 64, b = blockIdx.z;
    const int t = threadIdx.x;
    const int rlo = t >> 4, rhi = t & 15;
    if (blockIdx.x == 0 && blockIdx.y == 0) {   // fold source-table prep in
        const float* x2 = xyz2 + b * 3 * kS;
        for (int s = t; s < kS; s += 256) {
            float sx = x2[s], sy = x2[kS + s], sz = x2[2 * kS + s];
            f32x4 q = {sx, sy, sz, fmaf(sx, sx, fmaf(sy, sy, sz * sz))};
            spk[b * kS + s] = q;
        }
    }
#pragma unroll
    for (int r = 0; r < 4; ++r) {
        const int cl = rlo + r * 16;
        f32x4 v = *(const f32x4*)(in + ((size_t)(b * kD2 + c0 + cl)) * kS + s0 + rhi * 4);
#pragma unroll
        for (int j = 0; j < 4; ++j) tl[cl][rhi * 4 + j] = v[j];
    }
    __syncthreads();
#pragma unroll
    for (int r = 0; r < 4; ++r) {
        const int sl = rlo + r * 16;
        f32x4 v;
#pragma unroll
        for (int j = 0; j < 4; ++j) v[j] = tl[rhi * 4 + j][sl];
        *(f32x4*)(out + ((size_t)(b * kS + s0 + sl)) * kD2 + c0 + rhi * 4) = v;
    }
}

// ------------- Transpose points1 [b][c][n] -> xt[b][n][256+c] (bf16) -------
__global__ __launch_bounds__(256) void transpose_p1_kernel(
    const float* __restrict__ in, unsigned short* __restrict__ xt)
{
    __shared__ float tl[64][69];
    const int n0 = blockIdx.x * 64, c0 = blockIdx.y * 64, b = blockIdx.z;
    const int t = threadIdx.x;
    const int rlo = t >> 4, rhi = t & 15;
#pragma unroll
    for (int r = 0; r < 4; ++r) {
        const int cl = rlo + r * 16;
        f32x4 v = *(const f32x4*)(in + ((size_t)(b * kD1 + c0 + cl)) * kN + n0 + rhi * 4);
#pragma unroll
        for (int j = 0; j < 4; ++j) tl[cl][rhi * 4 + j] = v[j];
    }
    __syncthreads();
#pragma unroll
    for (int r = 0; r < 4; ++r) {
        const int nl = rlo + r * 16;
        u16x4 u;
#pragma unroll
        for (int j = 0; j < 4; ++j) u[j] = f2bf(tl[rhi * 4 + j][nl]);
        *(u16x4*)(xt + ((size_t)(b * kN + n0 + nl)) * kCin + 256 + c0 + rhi * 4) = u;
    }
}

// ------- 3-NN + interp: register source tiles + v_readlane broadcast -------
// Block = 4 waves x 64 lanes; each lane owns ONE query; wave w scans sources
// [512w, 512w+512) in 8 tiles of 64. Tile load = ONE coalesced
// global_load_dwordx4 (lane l holds source l of the tile, spk L2-hot); then a
// fully-unrolled j-loop broadcasts lane j's source via v_readlane (pure VALU,
// no memory instruction per pair -> kills the r3 LDS-pipe bound and the r5
// scalar-load stalls).
// pass1: rotating 4 min-chains of reduced dist d' = |s|^2 - 2p.s (1 fmin/j).
//        3rd-smallest of the 4 chain minima (4 distinct elements) >= true
//        d'(3); cutoff = that + 1e-3 (fp32 err ~1e-5, margin 100x, validated
//        r2-r5).
// pass2: rescan tiles; df <= cutoff -> exact fp64 insert with global index,
//        strict '<' (stable ties). Cross-wave LDS merge with (d, idx) lex
//        order; quad-cooperative gather (both verbatim from r5, validated).
__global__ __launch_bounds__(256) void knn_interp_kernel(
    const float* __restrict__ xyz1, const f32x4* __restrict__ spk,
    const float* __restrict__ p2t, unsigned short* __restrict__ xt)
{
    __shared__ double md[4][64][3];
    __shared__ int    mi[4][64][3];
    __shared__ float  gw[64][3];
    __shared__ int    gi[64][3];
    const int b = blockIdx.x >> 7;           // 128 blocks per batch
    const int n0 = (blockIdx.x & 127) << 6;  // 64 queries per block
    const int t = threadIdx.x;
    const int w = t >> 6, l = t & 63;
    const int n = n0 + l;
    const float* x1 = xyz1 + b * 3 * kN;
    const float px = x1[n], py = x1[kN + n], pz = x1[2 * kN + n];
    const float ax = -2.f * px, ay = -2.f * py, az = -2.f * pz;
    const f32x4* sb = spk + b * kS + w * 512;   // this wave's source subset

    // ---- pass 1: rotating 4 min-chains, readlane-broadcast tiles
    float c0 = 1e30f, c1 = 1e30f, c2 = 1e30f, c3 = 1e30f;
#pragma unroll 1
    for (int tle = 0; tle < 8; ++tle) {
        const f32x4 tv = sb[tle * 64 + l];
#pragma unroll
        for (int j = 0; j < 64; ++j) {
            const float sx = rdlane(tv[0], j), sy = rdlane(tv[1], j);
            const float sz = rdlane(tv[2], j), sn = rdlane(tv[3], j);
            const float e = fmaf(ax, sx, fmaf(ay, sy, fmaf(az, sz, sn)));
            if ((j & 3) == 0)      c0 = fminf(c0, e);
            else if ((j & 3) == 1) c1 = fminf(c1, e);
            else if ((j & 3) == 2) c2 = fminf(c2, e);
            else                   c3 = fminf(c3, e);
        }
    }
    const float hi1 = fmaxf(c0, c1), lo1 = fminf(c0, c1);
    const float hi2 = fmaxf(c2, c3), lo2 = fminf(c2, c3);
    const float bound3 = fmaxf(fminf(hi1, hi2), fmaxf(lo1, lo2));
    const float cutoff = bound3 + 1e-3f;

    // ---- pass 2: exact fp64 top-3 (global indices) among filtered candidates
    double d0 = 1e300, d1 = 1e300, d2 = 1e300;
    int i0 = 0, i1 = 0, i2 = 0;
    const double dpx = (double)px, dpy = (double)py, dpz = (double)pz;
#pragma unroll 1
    for (int tle = 0; tle < 8; ++tle) {
        const f32x4 tv = sb[tle * 64 + l];
#pragma unroll
        for (int j = 0; j < 64; ++j) {
            const float sx = rdlane(tv[0], j), sy = rdlane(tv[1], j);
            const float sz = rdlane(tv[2], j), sn = rdlane(tv[3], j);
            const float df = fmaf(ax, sx, fmaf(ay, sy, fmaf(az, sz, sn)));
            if (df <= cutoff) {
                const int s = w * 512 + tle * 64 + j;
                double ex = dpx - (double)sx, ey = dpy - (double)sy, ez = dpz - (double)sz;
                double d = ex * ex + ey * ey + ez * ez;
                if (d < d2) {
                    if (d < d1) {
                        if (d < d0) { d2 = d1; i2 = i1; d1 = d0; i1 = i0; d0 = d; i0 = s; }
                        else        { d2 = d1; i2 = i1; d1 = d;  i1 = s; }
                    } else          { d2 = d;  i2 = s; }
                }
            }
        }
    }
    md[w][l][0] = d0; md[w][l][1] = d1; md[w][l][2] = d2;
    mi[w][l][0] = i0; mi[w][l][1] = i1; mi[w][l][2] = i2;
    __syncthreads();

    // ---- cross-wave merge (wave 0), weights, publish to LDS
    if (w == 0) {
#pragma unroll
        for (int ww = 1; ww < 4; ++ww) {
#pragma unroll
            for (int m = 0; m < 3; ++m) {
                double pd = md[ww][l][m];
                int pi = mi[ww][l][m];
                if (pd < d2 || (pd == d2 && pi < i2)) {
                    if (pd < d1 || (pd == d1 && pi < i1)) {
                        if (pd < d0 || (pd == d0 && pi < i0)) {
                            d2 = d1; i2 = i1; d1 = d0; i1 = i0; d0 = pd; i0 = pi;
                        } else { d2 = d1; i2 = i1; d1 = pd; i1 = pi; }
                    } else { d2 = pd; i2 = pi; }
                }
            }
        }
        const double r0 = 1.0 / (d0 + 1e-8), r1 = 1.0 / (d1 + 1e-8), r2 = 1.0 / (d2 + 1e-8);
        const double rs = 1.0 / (r0 + r1 + r2);
        gw[l][0] = (float)(r0 * rs); gw[l][1] = (float)(r1 * rs); gw[l][2] = (float)(r2 * rs);
        gi[l][0] = i0; gi[l][1] = i1; gi[l][2] = i2;
    }
    __syncthreads();

    // ---- gather: 3 contiguous 1 KB p2t rows per query, quad-cooperative
    const int q = t >> 2, c4 = t & 3;
    const int nn = n0 + q;
    const float ww0 = gw[q][0], ww1 = gw[q][1], ww2 = gw[q][2];
    const f32x4* row0 = (const f32x4*)(p2t + ((size_t)(b * kS) + gi[q][0]) * kD2);
    const f32x4* row1 = (const f32x4*)(p2t + ((size_t)(b * kS) + gi[q][1]) * kD2);
    const f32x4* row2 = (const f32x4*)(p2t + ((size_t)(b * kS) + gi[q][2]) * kD2);
    unsigned short* dst = xt + ((size_t)(b * kN) + nn) * kCin;
#pragma unroll 4
    for (int j = 0; j < 16; ++j) {
        const int ch = c4 + 4 * j;                  // f32x4 chunk index (0..63)
        f32x4 v = ww0 * row0[ch] + ww1 * row1[ch] + ww2 * row2[ch];
        u16x4 u = {f2bf(v[0]), f2bf(v[1]), f2bf(v[2]), f2bf(v[3])};
        *(u16x4*)(dst + ch * 4) = u;
    }
}

// ---------------- bf16 MFMA GEMM + BN-stats --------------------------------
// X rows [n][K] bf16. W [MTOT][K] f32 -> bf16 on stage. 128x128 tile, 4 waves,
// 16x16x32 MFMA, XOR-swizzled LDS.
// BNRELU: apply input-side scale/shift + relu while staging X.
// OUTMODE: 0 = bf16 Yb[b][n][m]; 2 = no store (stats-only pass);
//          3 = f32 Yf[b][m][n] with output-side scaleO/shiftO + relu.
__device__ inline int swz(int row, int ks) {   // ushort index of a 16B slot
    return row * 32 + ((ks ^ ((row >> 1) & 3)) << 3);
}

template <int K, int MTOT, bool BNRELU, int OUTMODE, bool STATS>
__global__ __launch_bounds__(256) void gemm_bn_kernel(
    const float* __restrict__ W, const unsigned short* __restrict__ X,
    const float* __restrict__ scale, const float* __restrict__ shift,
    const float* __restrict__ scaleO, const float* __restrict__ shiftO,
    unsigned short* __restrict__ Yb, float* __restrict__ Yf,
    float* __restrict__ gsum, float* __restrict__ gsq)
{
    constexpr int BM = 128, BN = 128;
    __shared__ unsigned short Al[BM * 32], Bl[BN * 32];   // 8 KB each, swizzled
    __shared__ float ssum[BM], ssq[BM];
    __shared__ float s_sc[K > 0 ? K : 1], s_sh[K > 0 ? K : 1];
    __shared__ float s_scO[BM], s_shO[BM];
    const int t = threadIdx.x;
    const int bn = blockIdx.x * BN, bo = blockIdx.y * BM, b = blockIdx.z;
    const int l = t & 63, w = t >> 6;
    const int wm = (w >> 1) * 64, wn = (w & 1) * 64;
    const int lrow = l & 15, lks = l >> 4;

    if constexpr (BNRELU) {
        if (t < K) { s_sc[t] = scale[t]; s_sh[t] = shift[t]; }
    }
    if constexpr (OUTMODE == 3) {
        if (t < BM) { s_scO[t] = scaleO[bo + t]; s_shO[t] = shiftO[bo + t]; }
    }
    if constexpr (STATS) {
        if (t < BM) { ssum[t] = 0.f; ssq[t] = 0.f; }
    }
    __syncthreads();

    f32x4 acc[4][4] = {};
    for (int k0 = 0; k0 < K; k0 += 32) {
#pragma unroll
        for (int r = 0; r < 2; ++r) {
            const int sid = t + r * 256;
            const int m = sid >> 2, ks = sid & 3;
            const float* wp = W + (size_t)(bo + m) * K + k0 + ks * 8;
            f32x4 wa = *(const f32x4*)wp, wb = *(const f32x4*)(wp + 4);
            bf16x8 u;
#pragma unroll
            for (int j = 0; j < 4; ++j) { u[j] = (short)f2bf(wa[j]); u[j + 4] = (short)f2bf(wb[j]); }
            *(bf16x8*)(Al + swz(m, ks)) = u;
        }
#pragma unroll
        for (int r = 0; r < 2; ++r) {
            const int sid = t + r * 256;
            const int nl = sid >> 2, ks = sid & 3;
            bf16x8 v = *(const bf16x8*)(X + ((size_t)(b * kN) + bn + nl) * K + k0 + ks * 8);
            if constexpr (BNRELU) {
#pragma unroll
                for (int j = 0; j < 8; ++j) {
                    const int ch = k0 + ks * 8 + j;
                    float f = fmaxf(fmaf(bf2f((unsigned short)v[j]), s_sc[ch], s_sh[ch]), 0.f);
                    v[j] = (short)f2bf(f);
                }
            }
            *(bf16x8*)(Bl + swz(nl, ks)) = v;
        }
        __syncthreads();
        bf16x8 af[4], bfr[4];
#pragma unroll
        for (int f = 0; f < 4; ++f) af[f]  = *(const bf16x8*)(Al + swz(wm + f * 16 + lrow, lks));
#pragma unroll
        for (int f = 0; f < 4; ++f) bfr[f] = *(const bf16x8*)(Bl + swz(wn + f * 16 + lrow, lks));
#pragma unroll
        for (int mi = 0; mi < 4; ++mi)
#pragma unroll
            for (int ni = 0; ni < 4; ++ni)
                acc[mi][ni] = __builtin_amdgcn_mfma_f32_16x16x32_bf16(af[mi], bfr[ni], acc[mi][ni], 0, 0, 0);
        __syncthreads();
    }

    if constexpr (STATS) {
#pragma unroll
        for (int mi = 0; mi < 4; ++mi) {
#pragma unroll
            for (int r = 0; r < 4; ++r) {
                float ps = 0.f, pq = 0.f;
#pragma unroll
                for (int ni = 0; ni < 4; ++ni) { float v = acc[mi][ni][r]; ps += v; pq += v * v; }
#pragma unroll
                for (int off = 1; off < 16; off <<= 1) { ps += __shfl_xor(ps, off); pq += __shfl_xor(pq, off); }
                if (lrow == 0) {
                    const int m = wm + mi * 16 + lks * 4 + r;
                    atomicAdd(&ssum[m], ps); atomicAdd(&ssq[m], pq);
                }
            }
        }
    }

    if constexpr (OUTMODE == 0) {
#pragma unroll
        for (int mi = 0; mi < 4; ++mi)
#pragma unroll
            for (int ni = 0; ni < 4; ++ni) {
                const int m = bo + wm + mi * 16 + lks * 4;
                const int n = bn + wn + ni * 16 + lrow;
                u16x4 u = {f2bf(acc[mi][ni][0]), f2bf(acc[mi][ni][1]),
                           f2bf(acc[mi][ni][2]), f2bf(acc[mi][ni][3])};
                *(u16x4*)(Yb + ((size_t)(b * kN) + n) * MTOT + m) = u;
            }
    } else if constexpr (OUTMODE == 3) {
#pragma unroll
        for (int mi = 0; mi < 4; ++mi)
#pragma unroll
            for (int ni = 0; ni < 4; ++ni) {
                const int n = bn + wn + ni * 16 + lrow;
#pragma unroll
                for (int r = 0; r < 4; ++r) {
                    const int ml = wm + mi * 16 + lks * 4 + r;
                    float v = fmaxf(fmaf(acc[mi][ni][r], s_scO[ml], s_shO[ml]), 0.f);
                    Yf[((size_t)(b * MTOT) + bo + ml) * kN + n] = v;
                }
            }
    }
    if constexpr (STATS) {
        __syncthreads();
        if (t < BM) {
            atomicAdd(&gsum[bo + t], ssum[t]);
            atomicAdd(&gsq[bo + t], ssq[t]);
        }
    }
}

// ---------------- BN stat finalize -----------------------------------------
__global__ void bn_finalize_kernel(const float* __restrict__ gsum, const float* __restrict__ gsq,
                                   const float* __restrict__ g, const float* __restrict__ be,
                                   float* __restrict__ scale, float* __restrict__ shift, int M)
{
    int t = threadIdx.x;
    if (t < M) {
        const float invn = 1.0f / 65536.0f;
        float mean = gsum[t] * invn;
        float var = gsq[t] * invn - mean * mean;   // biased var
        float sc = g[t] * rsqrtf(var + kEps);
        scale[t] = sc;
        shift[t] = fmaf(-mean, sc, be[t]);
    }
}

extern "C" void kernel_launch(void* const* d_in, const int* in_sizes, int n_in,
                              void* d_out, int out_size, void* d_ws, size_t ws_size,
                              hipStream_t stream)
{
    const float* xyz1    = (const float*)d_in[0];
    const float* xyz2    = (const float*)d_in[1];
    const float* points1 = (const float*)d_in[2];
    const float* points2 = (const float*)d_in[3];
    const float* w0      = (const float*)d_in[4];
    // d_in[5] = b0, d_in[9] = b1: conv biases cancel in BatchNorm -> unused
    const float* g0      = (const float*)d_in[6];
    const float* be0     = (const float*)d_in[7];
    const float* w1      = (const float*)d_in[8];
    const float* g1      = (const float*)d_in[10];
    const float* be1     = (const float*)d_in[11];
    float* out = (float*)d_out;

    char* ws = (char*)d_ws;
    unsigned short* xt  = (unsigned short*)ws;                           // 48 MiB  [B][N][384] bf16
    float* p2t          = (float*)(ws + (size_t)50331648);               // 16 MiB  [B][S][256] f32
    unsigned short* y0t = (unsigned short*)(ws + (size_t)67108864);      // 32 MiB  [B][N][256] bf16
    float* stats        = (float*)(ws + (size_t)100663296);              // ~6 KB
    f32x4* spk          = (f32x4*)(ws + (size_t)104857600);              // 256 KiB [B][S] packed
    float* sum0 = stats,          *sq0 = stats + 256;
    float* sum1 = stats + 512,    *sq1 = stats + 640;
    float* scale0 = stats + 768,  *shift0 = stats + 1024;
    float* scale1 = stats + 1280, *shift1 = stats + 1408;

    hipMemsetAsync(stats, 0, 768 * sizeof(float), stream);
    transpose_p2_kernel<<<dim3(32, 4, 8), 256, 0, stream>>>(points2, p2t, xyz2, spk);
    transpose_p1_kernel<<<dim3(128, 2, 8), 256, 0, stream>>>(points1, xt);
    knn_interp_kernel<<<1024, 256, 0, stream>>>(xyz1, spk, p2t, xt);
    gemm_bn_kernel<kCin, kM0, false, 0, true><<<dim3(64, 2, 8), 256, 0, stream>>>(
        w0, xt, nullptr, nullptr, nullptr, nullptr, y0t, nullptr, sum0, sq0);
    bn_finalize_kernel<<<1, 256, 0, stream>>>(sum0, sq0, g0, be0, scale0, shift0, 256);
    gemm_bn_kernel<kM0, kM1, true, 2, true><<<dim3(64, 1, 8), 256, 0, stream>>>(
        w1, y0t, scale0, shift0, nullptr, nullptr, nullptr, nullptr, sum1, sq1);
    bn_finalize_kernel<<<1, 128, 0, stream>>>(sum1, sq1, g1, be1, scale1, shift1, 128);
    gemm_bn_kernel<kM0, kM1, true, 3, false><<<dim3(64, 1, 8), 256, 0, stream>>>(
        w1, y0t, scale0, shift0, scale1, shift1, nullptr, out, nullptr, nullptr);
}

// Round 7
// 209.816 us; speedup vs baseline: 1.3201x; 1.1243x over previous
//
#include <hip/hip_runtime.h>
#include <hip/hip_bf16.h>

constexpr int kB = 8, kN = 8192, kS = 2048;
constexpr int kD1 = 128, kD2 = 256, kCin = 384, kM0 = 256, kM1 = 128;
constexpr float kEps = 1e-5f;

typedef float f32x4 __attribute__((ext_vector_type(4)));
typedef short bf16x8 __attribute__((ext_vector_type(8)));
typedef unsigned short u16x4 __attribute__((ext_vector_type(4)));

__device__ inline unsigned short f2bf(float f) {
    __hip_bfloat16 h = __float2bfloat16(f);
    return *reinterpret_cast<unsigned short*>(&h);
}
__device__ inline float bf2f(unsigned short u) {
    unsigned int v = (unsigned int)u << 16;
    return *reinterpret_cast<float*>(&v);
}
__device__ inline float rdlane(float v, int j) {   // wave-uniform broadcast, VALU-domain
    return __int_as_float(__builtin_amdgcn_readlane(__float_as_int(v), j));
}

// ------- Transpose points2 [b][c][s] -> p2t [b][s][c] (f32), + spk prep ----
// spk[b][s] = (sx, sy, sz, |s|^2): packed source table, 32 KB/batch (L2-hot).
__global__ __launch_bounds__(256) void transpose_p2_kernel(
    const float* __restrict__ in, float* __restrict__ out,
    const float* __restrict__ xyz2, f32x4* __restrict__ spk)
{
    __shared__ float tl[64][69];
    const int s0 = blockIdx.x * 64, c0 = blockIdx.y * 64, b = blockIdx.z;
    const int t = threadIdx.x;
    const int rlo = t >> 4, rhi = t & 15;
    if (blockIdx.x == 0 && blockIdx.y == 0) {   // fold source-table prep in
        const float* x2 = xyz2 + b * 3 * kS;
        for (int s = t; s < kS; s += 256) {
            float sx = x2[s], sy = x2[kS + s], sz = x2[2 * kS + s];
            f32x4 q = {sx, sy, sz, fmaf(sx, sx, fmaf(sy, sy, sz * sz))};
            spk[b * kS + s] = q;
        }
    }
#pragma unroll
    for (int r = 0; r < 4; ++r) {
        const int cl = rlo + r * 16;
        f32x4 v = *(const f32x4*)(in + ((size_t)(b * kD2 + c0 + cl)) * kS + s0 + rhi * 4);
#pragma unroll
        for (int j = 0; j < 4; ++j) tl[cl][rhi * 4 + j] = v[j];
    }
    __syncthreads();
#pragma unroll
    for (int r = 0; r < 4; ++r) {
        const int sl = rlo + r * 16;
        f32x4 v;
#pragma unroll
        for (int j = 0; j < 4; ++j) v[j] = tl[rhi * 4 + j][sl];
        *(f32x4*)(out + ((size_t)(b * kS + s0 + sl)) * kD2 + c0 + rhi * 4) = v;
    }
}

// ------------- Transpose points1 [b][c][n] -> xt[b][n][256+c] (bf16) -------
__global__ __launch_bounds__(256) void transpose_p1_kernel(
    const float* __restrict__ in, unsigned short* __restrict__ xt)
{
    __shared__ float tl[64][69];
    const int n0 = blockIdx.x * 64, c0 = blockIdx.y * 64, b = blockIdx.z;
    const int t = threadIdx.x;
    const int rlo = t >> 4, rhi = t & 15;
#pragma unroll
    for (int r = 0; r < 4; ++r) {
        const int cl = rlo + r * 16;
        f32x4 v = *(const f32x4*)(in + ((size_t)(b * kD1 + c0 + cl)) * kN + n0 + rhi * 4);
#pragma unroll
        for (int j = 0; j < 4; ++j) tl[cl][rhi * 4 + j] = v[j];
    }
    __syncthreads();
#pragma unroll
    for (int r = 0; r < 4; ++r) {
        const int nl = rlo + r * 16;
        u16x4 u;
#pragma unroll
        for (int j = 0; j < 4; ++j) u[j] = f2bf(tl[rhi * 4 + j][nl]);
        *(u16x4*)(xt + ((size_t)(b * kN + n0 + nl)) * kCin + 256 + c0 + rhi * 4) = u;
    }
}

// ------- 3-NN + interp: SINGLE-PASS packed-key top-4, readlane tiles -------
// Lane owns a query; wave w scans sources [512w,512w+512) via readlane
// broadcast (r6, validated). Hot loop is branchless: full squared distance
// e = |s|^2 - 2p.s + |p|^2 >= 0 (clamped) so IEEE bits are uint-ordered;
// key = (bits(e) & ~2047) | src_idx -> u32 compare = lex (trunc-d, idx),
// exactly lax.top_k's stable order. Branchless top-4 u32 insert (min +
// 3x(max,min)). NO fp64 / NO divergence in the loop (r6's pass-2 cost).
// Wave0 merges 4x top-4, fp64-rescores+sorts the top-3 (exact order), and
// CERTIFIES set membership: gap(v3-v2) > 2.5e-4 + 1e-3*v3 covers 2x(fp32
// eps + 11-bit quantization). Uncertified queries (~2-5%) are ballot-
// compacted to a list; knn_fallback_kernel redoes them exactly in fp64.
__global__ __launch_bounds__(256) void knn_interp_kernel(
    const float* __restrict__ xyz1, const f32x4* __restrict__ spk,
    const float* __restrict__ p2t, unsigned short* __restrict__ xt,
    int* __restrict__ flaglist, int* __restrict__ flagcount)
{
    __shared__ unsigned int kk[4][64][4];
    __shared__ float gw[64][3];
    __shared__ int   gi[64][3];
    const int b = blockIdx.x >> 7;           // 128 blocks per batch
    const int n0 = (blockIdx.x & 127) << 6;  // 64 queries per block
    const int t = threadIdx.x;
    const int w = t >> 6, l = t & 63;
    const int n = n0 + l;
    const float* x1 = xyz1 + b * 3 * kN;
    const float px = x1[n], py = x1[kN + n], pz = x1[2 * kN + n];
    const float ax = -2.f * px, ay = -2.f * py, az = -2.f * pz;
    const float pp = fmaf(px, px, fmaf(py, py, pz * pz));
    const f32x4* sb = spk + b * kS + w * 512;   // this wave's source subset

    unsigned int k0 = 0xFFFFFFFFu, k1 = 0xFFFFFFFFu, k2 = 0xFFFFFFFFu, k3 = 0xFFFFFFFFu;
#pragma unroll 1
    for (int tle = 0; tle < 8; ++tle) {
        const f32x4 tv = sb[tle * 64 + l];
        const unsigned int sbase = (unsigned)(w * 512 + tle * 64);
#pragma unroll
        for (int j = 0; j < 64; ++j) {
            const float sx = rdlane(tv[0], j), sy = rdlane(tv[1], j);
            const float sz = rdlane(tv[2], j), sn = rdlane(tv[3], j);
            float e = fmaf(ax, sx, fmaf(ay, sy, fmaf(az, sz, sn + pp)));
            e = fmaxf(e, 0.f);
            const unsigned int key = (__float_as_uint(e) & 0xFFFFF800u) | (sbase + j);
            const unsigned int x = key;
            k3 = min(max(x, k2), k3);
            k2 = min(max(x, k1), k2);
            k1 = min(max(x, k0), k1);
            k0 = min(x, k0);
        }
    }
    kk[w][l][0] = k0; kk[w][l][1] = k1; kk[w][l][2] = k2; kk[w][l][3] = k3;
    __syncthreads();

    if (w == 0) {
        // merge the other 3 waves' sorted top-4 (u32 lex order is global)
#pragma unroll
        for (int ww = 1; ww < 4; ++ww) {
#pragma unroll
            for (int m = 0; m < 4; ++m) {
                const unsigned int x = kk[ww][l][m];
                k3 = min(max(x, k2), k3);
                k2 = min(max(x, k1), k2);
                k1 = min(max(x, k0), k1);
                k0 = min(x, k0);
            }
        }
        int i0 = (int)(k0 & 2047u), i1 = (int)(k1 & 2047u), i2 = (int)(k2 & 2047u);
        const float v2t = __uint_as_float(k2 & 0xFFFFF800u);
        const float v3t = __uint_as_float(k3 & 0xFFFFF800u);
        const bool flag = (v3t - v2t) <= fmaf(v3t, 1e-3f, 2.5e-4f);

        // fp64 rescore of the 3 chosen: exact order, exact weights
        const double dpx = (double)px, dpy = (double)py, dpz = (double)pz;
        const f32x4 q0 = spk[b * kS + i0], q1 = spk[b * kS + i1], q2 = spk[b * kS + i2];
        double d0 = (dpx - q0[0]) * (dpx - q0[0]) + (dpy - q0[1]) * (dpy - q0[1]) + (dpz - q0[2]) * (dpz - q0[2]);
        double d1 = (dpx - q1[0]) * (dpx - q1[0]) + (dpy - q1[1]) * (dpy - q1[1]) + (dpz - q1[2]) * (dpz - q1[2]);
        double d2 = (dpx - q2[0]) * (dpx - q2[0]) + (dpy - q2[1]) * (dpy - q2[1]) + (dpz - q2[2]) * (dpz - q2[2]);
        if (d1 < d0 || (d1 == d0 && i1 < i0)) { double td = d0; d0 = d1; d1 = td; int ti = i0; i0 = i1; i1 = ti; }
        if (d2 < d1 || (d2 == d1 && i2 < i1)) { double td = d1; d1 = d2; d2 = td; int ti = i1; i1 = i2; i2 = ti; }
        if (d1 < d0 || (d1 == d0 && i1 < i0)) { double td = d0; d0 = d1; d1 = td; int ti = i0; i0 = i1; i1 = ti; }
        const double r0 = 1.0 / (d0 + 1e-8), r1 = 1.0 / (d1 + 1e-8), r2 = 1.0 / (d2 + 1e-8);
        const double rs = 1.0 / (r0 + r1 + r2);
        gw[l][0] = (float)(r0 * rs); gw[l][1] = (float)(r1 * rs); gw[l][2] = (float)(r2 * rs);
        gi[l][0] = i0; gi[l][1] = i1; gi[l][2] = i2;

        // compact flagged queries (rare): ballot + one atomic per wave
        const unsigned long long bal = __ballot(flag);
        if (bal) {
            int base = 0;
            if (l == 0) base = atomicAdd(flagcount, __popcll(bal));
            base = __shfl(base, 0);
            if (flag) {
                const int pre = __popcll(bal & ((1ull << l) - 1ull));
                flaglist[base + pre] = (b << 13) | n;
            }
        }
    }
    __syncthreads();

    // gather: 3 contiguous 1 KB p2t rows per query, quad-cooperative
    const int q = t >> 2, c4 = t & 3;
    const int nn = n0 + q;
    const float ww0 = gw[q][0], ww1 = gw[q][1], ww2 = gw[q][2];
    const f32x4* row0 = (const f32x4*)(p2t + ((size_t)(b * kS) + gi[q][0]) * kD2);
    const f32x4* row1 = (const f32x4*)(p2t + ((size_t)(b * kS) + gi[q][1]) * kD2);
    const f32x4* row2 = (const f32x4*)(p2t + ((size_t)(b * kS) + gi[q][2]) * kD2);
    unsigned short* dst = xt + ((size_t)(b * kN) + nn) * kCin;
#pragma unroll 4
    for (int j = 0; j < 16; ++j) {
        const int ch = c4 + 4 * j;                  // f32x4 chunk index (0..63)
        f32x4 v = ww0 * row0[ch] + ww1 * row1[ch] + ww2 * row2[ch];
        u16x4 u = {f2bf(v[0]), f2bf(v[1]), f2bf(v[2]), f2bf(v[3])};
        *(u16x4*)(dst + ch * 4) = u;
    }
}

// ---- Exact fp64 redo for uncertified queries (one wave per query) ---------
// Grid-stride over the compacted list; lanes split sources (l, l+64, ...),
// exact fp64 (d, idx) lex top-3 with 6-level butterfly merge, then the
// 64-lane cooperative gather overwrites the query's xt row.
__global__ __launch_bounds__(256) void knn_fallback_kernel(
    const float* __restrict__ xyz1, const f32x4* __restrict__ spk,
    const float* __restrict__ p2t, unsigned short* __restrict__ xt,
    const int* __restrict__ flaglist, const int* __restrict__ flagcount)
{
    const int cnt = *flagcount;
    const int t = threadIdx.x;
    const int w = t >> 6, l = t & 63;
    for (int idx = blockIdx.x * 4 + w; idx < cnt; idx += gridDim.x * 4) {
        const int code = flaglist[idx];
        const int b = code >> 13, n = code & 8191;
        const float* x1 = xyz1 + b * 3 * kN;
        const double px = (double)x1[n], py = (double)x1[kN + n], pz = (double)x1[2 * kN + n];
        double d0 = 1e300, d1 = 1e300, d2 = 1e300;
        int i0 = 0, i1 = 0, i2 = 0;
        for (int s = l; s < kS; s += 64) {
            const f32x4 q = spk[b * kS + s];
            const double ex = px - (double)q[0], ey = py - (double)q[1], ez = pz - (double)q[2];
            const double d = ex * ex + ey * ey + ez * ez;
            if (d < d2) {
                if (d < d1) {
                    if (d < d0) { d2 = d1; i2 = i1; d1 = d0; i1 = i0; d0 = d; i0 = s; }
                    else        { d2 = d1; i2 = i1; d1 = d;  i1 = s; }
                } else          { d2 = d;  i2 = s; }
            }
        }
#pragma unroll
        for (int off = 1; off < 64; off <<= 1) {
            double pd0 = __shfl_xor(d0, off), pd1 = __shfl_xor(d1, off), pd2 = __shfl_xor(d2, off);
            int pi0 = __shfl_xor(i0, off), pi1 = __shfl_xor(i1, off), pi2 = __shfl_xor(i2, off);
#pragma unroll
            for (int m = 0; m < 3; ++m) {
                const double pd = (m == 0) ? pd0 : (m == 1) ? pd1 : pd2;
                const int pi = (m == 0) ? pi0 : (m == 1) ? pi1 : pi2;
                if (pd < d2 || (pd == d2 && pi < i2)) {
                    if (pd < d1 || (pd == d1 && pi < i1)) {
                        if (pd < d0 || (pd == d0 && pi < i0)) {
                            d2 = d1; i2 = i1; d1 = d0; i1 = i0; d0 = pd; i0 = pi;
                        } else { d2 = d1; i2 = i1; d1 = pd; i1 = pi; }
                    } else { d2 = pd; i2 = pi; }
                }
            }
        }
        const double r0 = 1.0 / (d0 + 1e-8), r1 = 1.0 / (d1 + 1e-8), r2 = 1.0 / (d2 + 1e-8);
        const double rs = 1.0 / (r0 + r1 + r2);
        const float w0f = (float)(r0 * rs), w1f = (float)(r1 * rs), w2f = (float)(r2 * rs);
        const f32x4* row0 = (const f32x4*)(p2t + ((size_t)(b * kS) + i0) * kD2);
        const f32x4* row1 = (const f32x4*)(p2t + ((size_t)(b * kS) + i1) * kD2);
        const f32x4* row2 = (const f32x4*)(p2t + ((size_t)(b * kS) + i2) * kD2);
        const f32x4 v = w0f * row0[l] + w1f * row1[l] + w2f * row2[l];
        u16x4 u = {f2bf(v[0]), f2bf(v[1]), f2bf(v[2]), f2bf(v[3])};
        *(u16x4*)(xt + ((size_t)(b * kN) + n) * kCin + l * 4) = u;
    }
}

// ---------------- bf16 MFMA GEMM + BN-stats (unchanged from r6) ------------
__device__ inline int swz(int row, int ks) {   // ushort index of a 16B slot
    return row * 32 + ((ks ^ ((row >> 1) & 3)) << 3);
}

template <int K, int MTOT, bool BNRELU, int OUTMODE, bool STATS>
__global__ __launch_bounds__(256) void gemm_bn_kernel(
    const float* __restrict__ W, const unsigned short* __restrict__ X,
    const float* __restrict__ scale, const float* __restrict__ shift,
    const float* __restrict__ scaleO, const float* __restrict__ shiftO,
    unsigned short* __restrict__ Yb, float* __restrict__ Yf,
    float* __restrict__ gsum, float* __restrict__ gsq)
{
    constexpr int BM = 128, BN = 128;
    __shared__ unsigned short Al[BM * 32], Bl[BN * 32];   // 8 KB each, swizzled
    __shared__ float ssum[BM], ssq[BM];
    __shared__ float s_sc[K > 0 ? K : 1], s_sh[K > 0 ? K : 1];
    __shared__ float s_scO[BM], s_shO[BM];
    const int t = threadIdx.x;
    const int bn = blockIdx.x * BN, bo = blockIdx.y * BM, b = blockIdx.z;
    const int l = t & 63, w = t >> 6;
    const int wm = (w >> 1) * 64, wn = (w & 1) * 64;
    const int lrow = l & 15, lks = l >> 4;

    if constexpr (BNRELU) {
        if (t < K) { s_sc[t] = scale[t]; s_sh[t] = shift[t]; }
    }
    if constexpr (OUTMODE == 3) {
        if (t < BM) { s_scO[t] = scaleO[bo + t]; s_shO[t] = shiftO[bo + t]; }
    }
    if constexpr (STATS) {
        if (t < BM) { ssum[t] = 0.f; ssq[t] = 0.f; }
    }
    __syncthreads();

    f32x4 acc[4][4] = {};
    for (int k0 = 0; k0 < K; k0 += 32) {
#pragma unroll
        for (int r = 0; r < 2; ++r) {
            const int sid = t + r * 256;
            const int m = sid >> 2, ks = sid & 3;
            const float* wp = W + (size_t)(bo + m) * K + k0 + ks * 8;
            f32x4 wa = *(const f32x4*)wp, wb = *(const f32x4*)(wp + 4);
            bf16x8 u;
#pragma unroll
            for (int j = 0; j < 4; ++j) { u[j] = (short)f2bf(wa[j]); u[j + 4] = (short)f2bf(wb[j]); }
            *(bf16x8*)(Al + swz(m, ks)) = u;
        }
#pragma unroll
        for (int r = 0; r < 2; ++r) {
            const int sid = t + r * 256;
            const int nl = sid >> 2, ks = sid & 3;
            bf16x8 v = *(const bf16x8*)(X + ((size_t)(b * kN) + bn + nl) * K + k0 + ks * 8);
            if constexpr (BNRELU) {
#pragma unroll
                for (int j = 0; j < 8; ++j) {
                    const int ch = k0 + ks * 8 + j;
                    float f = fmaxf(fmaf(bf2f((unsigned short)v[j]), s_sc[ch], s_sh[ch]), 0.f);
                    v[j] = (short)f2bf(f);
                }
            }
            *(bf16x8*)(Bl + swz(nl, ks)) = v;
        }
        __syncthreads();
        bf16x8 af[4], bfr[4];
#pragma unroll
        for (int f = 0; f < 4; ++f) af[f]  = *(const bf16x8*)(Al + swz(wm + f * 16 + lrow, lks));
#pragma unroll
        for (int f = 0; f < 4; ++f) bfr[f] = *(const bf16x8*)(Bl + swz(wn + f * 16 + lrow, lks));
#pragma unroll
        for (int mi = 0; mi < 4; ++mi)
#pragma unroll
            for (int ni = 0; ni < 4; ++ni)
                acc[mi][ni] = __builtin_amdgcn_mfma_f32_16x16x32_bf16(af[mi], bfr[ni], acc[mi][ni], 0, 0, 0);
        __syncthreads();
    }

    if constexpr (STATS) {
#pragma unroll
        for (int mi = 0; mi < 4; ++mi) {
#pragma unroll
            for (int r = 0; r < 4; ++r) {
                float ps = 0.f, pq = 0.f;
#pragma unroll
                for (int ni = 0; ni < 4; ++ni) { float v = acc[mi][ni][r]; ps += v; pq += v * v; }
#pragma unroll
                for (int off = 1; off < 16; off <<= 1) { ps += __shfl_xor(ps, off); pq += __shfl_xor(pq, off); }
                if (lrow == 0) {
                    const int m = wm + mi * 16 + lks * 4 + r;
                    atomicAdd(&ssum[m], ps); atomicAdd(&ssq[m], pq);
                }
            }
        }
    }

    if constexpr (OUTMODE == 0) {
#pragma unroll
        for (int mi = 0; mi < 4; ++mi)
#pragma unroll
            for (int ni = 0; ni < 4; ++ni) {
                const int m = bo + wm + mi * 16 + lks * 4;
                const int n = bn + wn + ni * 16 + lrow;
                u16x4 u = {f2bf(acc[mi][ni][0]), f2bf(acc[mi][ni][1]),
                           f2bf(acc[mi][ni][2]), f2bf(acc[mi][ni][3])};
                *(u16x4*)(Yb + ((size_t)(b * kN) + n) * MTOT + m) = u;
            }
    } else if constexpr (OUTMODE == 3) {
#pragma unroll
        for (int mi = 0; mi < 4; ++mi)
#pragma unroll
            for (int ni = 0; ni < 4; ++ni) {
                const int n = bn + wn + ni * 16 + lrow;
#pragma unroll
                for (int r = 0; r < 4; ++r) {
                    const int ml = wm + mi * 16 + lks * 4 + r;
                    float v = fmaxf(fmaf(acc[mi][ni][r], s_scO[ml], s_shO[ml]), 0.f);
                    Yf[((size_t)(b * MTOT) + bo + ml) * kN + n] = v;
                }
            }
    }
    if constexpr (STATS) {
        __syncthreads();
        if (t < BM) {
            atomicAdd(&gsum[bo + t], ssum[t]);
            atomicAdd(&gsq[bo + t], ssq[t]);
        }
    }
}

// ---------------- BN stat finalize -----------------------------------------
__global__ void bn_finalize_kernel(const float* __restrict__ gsum, const float* __restrict__ gsq,
                                   const float* __restrict__ g, const float* __restrict__ be,
                                   float* __restrict__ scale, float* __restrict__ shift, int M)
{
    int t = threadIdx.x;
    if (t < M) {
        const float invn = 1.0f / 65536.0f;
        float mean = gsum[t] * invn;
        float var = gsq[t] * invn - mean * mean;   // biased var
        float sc = g[t] * rsqrtf(var + kEps);
        scale[t] = sc;
        shift[t] = fmaf(-mean, sc, be[t]);
    }
}

extern "C" void kernel_launch(void* const* d_in, const int* in_sizes, int n_in,
                              void* d_out, int out_size, void* d_ws, size_t ws_size,
                              hipStream_t stream)
{
    const float* xyz1    = (const float*)d_in[0];
    const float* xyz2    = (const float*)d_in[1];
    const float* points1 = (const float*)d_in[2];
    const float* points2 = (const float*)d_in[3];
    const float* w0      = (const float*)d_in[4];
    // d_in[5] = b0, d_in[9] = b1: conv biases cancel in BatchNorm -> unused
    const float* g0      = (const float*)d_in[6];
    const float* be0     = (const float*)d_in[7];
    const float* w1      = (const float*)d_in[8];
    const float* g1      = (const float*)d_in[10];
    const float* be1     = (const float*)d_in[11];
    float* out = (float*)d_out;

    char* ws = (char*)d_ws;
    unsigned short* xt  = (unsigned short*)ws;                           // 48 MiB  [B][N][384] bf16
    float* p2t          = (float*)(ws + (size_t)50331648);               // 16 MiB  [B][S][256] f32
    unsigned short* y0t = (unsigned short*)(ws + (size_t)67108864);      // 32 MiB  [B][N][256] bf16
    float* stats        = (float*)(ws + (size_t)100663296);              // ~7 KB
    f32x4* spk          = (f32x4*)(ws + (size_t)104857600);              // 256 KiB [B][S] packed
    int*  flaglist      = (int*)(ws + (size_t)105906176);                // 256 KiB worst-case
    float* sum0 = stats,          *sq0 = stats + 256;
    float* sum1 = stats + 512,    *sq1 = stats + 640;
    float* scale0 = stats + 768,  *shift0 = stats + 1024;
    float* scale1 = stats + 1280, *shift1 = stats + 1408;
    int*  flagcount = (int*)(stats + 1536);

    hipMemsetAsync(stats, 0, 1792 * sizeof(float), stream);   // stats + flagcount
    transpose_p2_kernel<<<dim3(32, 4, 8), 256, 0, stream>>>(points2, p2t, xyz2, spk);
    transpose_p1_kernel<<<dim3(128, 2, 8), 256, 0, stream>>>(points1, xt);
    knn_interp_kernel<<<1024, 256, 0, stream>>>(xyz1, spk, p2t, xt, flaglist, flagcount);
    knn_fallback_kernel<<<1024, 256, 0, stream>>>(xyz1, spk, p2t, xt, flaglist, flagcount);
    gemm_bn_kernel<kCin, kM0, false, 0, true><<<dim3(64, 2, 8), 256, 0, stream>>>(
        w0, xt, nullptr, nullptr, nullptr, nullptr, y0t, nullptr, sum0, sq0);
    bn_finalize_kernel<<<1, 256, 0, stream>>>(sum0, sq0, g0, be0, scale0, shift0, 256);
    gemm_bn_kernel<kM0, kM1, true, 2, true><<<dim3(64, 1, 8), 256, 0, stream>>>(
        w1, y0t, scale0, shift0, nullptr, nullptr, nullptr, nullptr, sum1, sq1);
    bn_finalize_kernel<<<1, 128, 0, stream>>>(sum1, sq1, g1, be1, scale1, shift1, 128);
    gemm_bn_kernel<kM0, kM1, true, 3, false><<<dim3(64, 1, 8), 256, 0, stream>>>(
        w1, y0t, scale0, shift0, scale1, shift1, nullptr, out, nullptr, nullptr);
}